// Round 2
// baseline (450.488 us; speedup 1.0000x reference)
//
#include <hip/hip_runtime.h>
#include <hip/hip_cooperative_groups.h>
#include <math.h>

namespace cg = cooperative_groups;

#define IN_DIM 128
#define HID 64
#define HEADS 4
#define NEG_SLOPE 0.2f
#define LN_EPS 1e-5f
#define APAD 328            // Atile row pitch in bf16 elems (320 + 8 pad -> 2-way banks max)

typedef short bf16x8 __attribute__((ext_vector_type(8)));
typedef float f32x4  __attribute__((ext_vector_type(4)));
typedef unsigned short u16x4 __attribute__((ext_vector_type(4)));

// ---------- bf16 helpers ----------
__device__ inline unsigned short f2bf(float f) {
    unsigned u = __float_as_uint(f);
    u += 0x7fffu + ((u >> 16) & 1u);     // round-to-nearest-even
    return (unsigned short)(u >> 16);
}
__device__ inline float bf2f(unsigned short s) {
    return __uint_as_float(((unsigned)s) << 16);
}
__device__ inline float leaky(float v) { return v > 0.0f ? v : NEG_SLOPE * v; }

// ---------- cooperative front end: init/pack -> hist -> scan -> scatter + x@Wgcn ----------
// P1: zero hist, pack Wt_post/Wt_xw, fold att vectors, dtype detect (block 0)
// P2: dst histogram (atomics)
// P3: per-chunk exclusive scan -> tmp, chunk sums -> partial
// P4: every block redundantly scans partials (nch<=256), applies -> row_ptr/cursor/dinv
// P5: CSR scatter (atomic bump) + MFMA x@W_gcn -> xws (grid-stride tiles)
__global__ __launch_bounds__(256) void k_front(
        const void* ei, int E, int n,
        int* flag, int* hist, int* tmp, int* partial,
        int* row_ptr, int* cursor, int* col, float* dinv,
        const float* x,
        const float* Wg, const float* Wp, const float* Wgcn,
        const float* att_s, const float* att_d,
        unsigned short* Wt_post, unsigned short* Wt_xw,
        float* w_s, float* w_d,
        unsigned short* xws) {
    cg::grid_group grid = cg::this_grid();
    __shared__ int s[256];
    __shared__ int sp[256];
    __shared__ int s_bad;
    __shared__ unsigned short Wt[16 * 64 * 8];   // 16 KB
    int t = threadIdx.x;
    int B = gridDim.x;
    int T = B * 256;
    int g = blockIdx.x * 256 + t;

    // ---- P1 ----
    for (int i = g; i < n; i += T) hist[i] = 0;
    for (int p = g; p < 2560; p += T) {
        int c = p & 63, kg = p >> 6;
        bf16x8 v;
#pragma unroll
        for (int j = 0; j < 8; j++) {
            int k = kg * 8 + j;
            float f;
            if (k < 256) f = 0.25f * Wg[(size_t)(k & 63) * 256 + (k >> 6) * 64 + c];
            else         f = Wp[(size_t)(k - 256) * 64 + c];
            v[j] = (short)f2bf(f);
        }
        *(bf16x8*)(&Wt_post[(size_t)p * 8]) = v;
    }
    for (int q = g; q < 1024; q += T) {
        int c = q & 63, kg = q >> 6;
        bf16x8 v;
#pragma unroll
        for (int j = 0; j < 8; j++)
            v[j] = (short)f2bf(Wgcn[(size_t)(kg * 8 + j) * 64 + c]);
        *(bf16x8*)(&Wt_xw[(size_t)q * 8]) = v;
    }
    for (int idx = g; idx < 256; idx += T) {
        int h = idx >> 6, k = idx & 63;
        float ss = 0.0f, sd = 0.0f;
        for (int c = 0; c < HID; c++) {
            float w = Wg[(size_t)k * (HEADS * HID) + h * HID + c];
            ss += w * att_s[h * HID + c];
            sd += w * att_d[h * HID + c];
        }
        w_s[h * HID + k] = ss;
        w_d[h * HID + k] = sd;
    }
    if (blockIdx.x == 0) {
        if (t == 0) s_bad = 0;
        __syncthreads();
        int lim = E < 4096 ? E : 4096;
        int bad = 0;
        for (int k = t; k < lim; k += 256)
            if (((const unsigned long long*)ei)[k] >= (unsigned long long)n) bad = 1;
        if (bad) s_bad = 1;      // benign race
        __syncthreads();
        if (t == 0) *flag = s_bad ? 0 : 1;   // 1 = genuine int64
    }
    grid.sync();

    // ---- P2: histogram ----
    int is64 = *flag;
    for (int i = g; i < E; i += T) {
        int d;
        if (is64) d = (int)((const long long*)ei)[E + i];
        else      d = ((const int*)ei)[E + i];
        atomicAdd(&hist[d], 1);
    }
    grid.sync();

    // ---- P3: chunk scans ----
    int nch = (n + 255) >> 8;
    for (int c = blockIdx.x; c < nch; c += B) {
        int i = c * 256 + t;
        int v = (i < n) ? hist[i] : 0;
        s[t] = v;
        __syncthreads();
        for (int off = 1; off < 256; off <<= 1) {
            int xv = (t >= off) ? s[t - off] : 0;
            __syncthreads();
            s[t] += xv;
            __syncthreads();
        }
        tmp[i] = s[t] - v;
        if (t == 255) partial[c] = s[255];
        __syncthreads();
    }
    grid.sync();

    // ---- P4: scan partials (redundant per block) + apply ----
    {
        int v = (t < nch) ? partial[t] : 0;
        s[t] = v;
        __syncthreads();
        for (int off = 1; off < 256; off <<= 1) {
            int xv = (t >= off) ? s[t - off] : 0;
            __syncthreads();
            s[t] += xv;
            __syncthreads();
        }
        sp[t] = s[t];
        __syncthreads();
    }
    for (int c = blockIdx.x; c < nch; c += B) {
        int i = c * 256 + t;
        if (i < n) {
            int excl = (c == 0) ? 0 : sp[c - 1];
            int v2 = tmp[i] + excl;
            row_ptr[i] = v2;
            cursor[i] = v2;
            dinv[i] = rsqrtf((float)(hist[i] + 1));   // +1 self-loop
        }
    }
    grid.sync();

    // ---- P5: CSR scatter + MFMA x@W_gcn ----
    for (int i = g; i < E; i += T) {
        int ss, dd;
        if (is64) { ss = (int)((const long long*)ei)[i]; dd = (int)((const long long*)ei)[E + i]; }
        else      { ss = ((const int*)ei)[i];            dd = ((const int*)ei)[E + i]; }
        int pos = atomicAdd(&cursor[dd], 1);
        col[pos] = ss;
    }
    for (int idx = t; idx < 1024; idx += 256)    // stage Wt_xw (contiguous, conflict-free)
        *(bf16x8*)(&Wt[idx * 8]) = *(const bf16x8*)(&Wt_xw[(size_t)idx * 8]);
    __syncthreads();
    int lane = t & 63;
    int li = lane & 15, quad = lane >> 4;
    int wv = t >> 6;
    int ntile = (n + 63) >> 6;
    for (int bx = blockIdx.x; bx < ntile; bx += B) {
        int r0 = bx * 64 + wv * 16;
        int rload = r0 + li; if (rload > n - 1) rload = n - 1;
        f32x4 acc[4];
#pragma unroll
        for (int i = 0; i < 4; i++) acc[i] = (f32x4){0.f, 0.f, 0.f, 0.f};
        const float* xp = x + (size_t)rload * IN_DIM + quad * 8;
#pragma unroll
        for (int ks = 0; ks < 4; ks++) {
            float4 p0 = *(const float4*)(xp + ks * 32);
            float4 p1 = *(const float4*)(xp + ks * 32 + 4);
            bf16x8 a;
            a[0] = (short)f2bf(p0.x); a[1] = (short)f2bf(p0.y);
            a[2] = (short)f2bf(p0.z); a[3] = (short)f2bf(p0.w);
            a[4] = (short)f2bf(p1.x); a[5] = (short)f2bf(p1.y);
            a[6] = (short)f2bf(p1.z); a[7] = (short)f2bf(p1.w);
            int kg = ks * 4 + quad;
#pragma unroll
            for (int tt = 0; tt < 4; tt++) {
                bf16x8 bfr = *(const bf16x8*)(&Wt[((kg * 64) + tt * 16 + li) * 8]);
                acc[tt] = __builtin_amdgcn_mfma_f32_16x16x32_bf16(a, bfr, acc[tt], 0, 0, 0);
            }
        }
#pragma unroll
        for (int reg = 0; reg < 4; reg++) {
            int r = r0 + quad * 4 + reg;
            if (r >= n) continue;
            float dv = dinv[r];
#pragma unroll
            for (int tt = 0; tt < 4; tt++)
                xws[(size_t)r * HID + tt * 16 + li] = f2bf(acc[tt][reg] * dv);
        }
    }
}

// ---------- GCN gather: 4-edge-wide (quarter-wave per edge, 4 ch/lane) ----------
__global__ __launch_bounds__(256) void k_gcn(const int* __restrict__ col,
                                             const int* __restrict__ row_ptr,
                                             const int* __restrict__ hist,
                                             const float* __restrict__ dinv,
                                             const unsigned short* __restrict__ xws,
                                             const float* __restrict__ b,
                                             const float* __restrict__ w_s,
                                             const float* __restrict__ w_d,
                                             unsigned short* __restrict__ h1b,
                                             float4* __restrict__ a_s,
                                             float4* __restrict__ a_d, int n) {
    int t = threadIdx.x;
    int w = t >> 6, lane = t & 63, q = lane >> 4, li = lane & 15;
    int d = blockIdx.x * 4 + w;
    if (d >= n) return;
    int start = row_ptr[d], cnt = hist[d];
    float a0, a1, a2, a3;
    {
        u16x4 sv = *(const u16x4*)(xws + (size_t)d * HID + li * 4);
        float z = (q == 0) ? 1.0f : 0.0f;          // self term counted once
        a0 = z * bf2f(sv[0]); a1 = z * bf2f(sv[1]);
        a2 = z * bf2f(sv[2]); a3 = z * bf2f(sv[3]);
    }
    int k = q;
    int s = (k < cnt) ? col[start + k] : -1;
    while (s >= 0) {
        int k2 = k + 4;
        int s2 = (k2 < cnt) ? col[start + k2] : -1;   // prefetch next col chunk
        u16x4 v = *(const u16x4*)(xws + (size_t)s * HID + li * 4);
        a0 += bf2f(v[0]); a1 += bf2f(v[1]); a2 += bf2f(v[2]); a3 += bf2f(v[3]);
        k = k2; s = s2;
    }
    a0 += __shfl_xor(a0, 16, 64); a1 += __shfl_xor(a1, 16, 64);
    a2 += __shfl_xor(a2, 16, 64); a3 += __shfl_xor(a3, 16, 64);
    a0 += __shfl_xor(a0, 32, 64); a1 += __shfl_xor(a1, 32, 64);
    a2 += __shfl_xor(a2, 32, 64); a3 += __shfl_xor(a3, 32, 64);
    float dv = dinv[d];
    float4 bv = *(const float4*)(b + li * 4);
    float h0 = fmaxf(a0 * dv + bv.x, 0.0f);
    float h1 = fmaxf(a1 * dv + bv.y, 0.0f);
    float h2 = fmaxf(a2 * dv + bv.z, 0.0f);
    float h3 = fmaxf(a3 * dv + bv.w, 0.0f);
    if (q == 0) {
        u16x4 o;
        o[0] = f2bf(h0); o[1] = f2bf(h1); o[2] = f2bf(h2); o[3] = f2bf(h3);
        *(u16x4*)(h1b + (size_t)d * HID + li * 4) = o;
    }
    float4 u;
    u = *(const float4*)(w_s + 0 * 64 + li * 4);
    float vs0 = h0 * u.x + h1 * u.y + h2 * u.z + h3 * u.w;
    u = *(const float4*)(w_s + 1 * 64 + li * 4);
    float vs1 = h0 * u.x + h1 * u.y + h2 * u.z + h3 * u.w;
    u = *(const float4*)(w_s + 2 * 64 + li * 4);
    float vs2 = h0 * u.x + h1 * u.y + h2 * u.z + h3 * u.w;
    u = *(const float4*)(w_s + 3 * 64 + li * 4);
    float vs3 = h0 * u.x + h1 * u.y + h2 * u.z + h3 * u.w;
    u = *(const float4*)(w_d + 0 * 64 + li * 4);
    float vd0 = h0 * u.x + h1 * u.y + h2 * u.z + h3 * u.w;
    u = *(const float4*)(w_d + 1 * 64 + li * 4);
    float vd1 = h0 * u.x + h1 * u.y + h2 * u.z + h3 * u.w;
    u = *(const float4*)(w_d + 2 * 64 + li * 4);
    float vd2 = h0 * u.x + h1 * u.y + h2 * u.z + h3 * u.w;
    u = *(const float4*)(w_d + 3 * 64 + li * 4);
    float vd3 = h0 * u.x + h1 * u.y + h2 * u.z + h3 * u.w;
#pragma unroll
    for (int o = 1; o <= 8; o <<= 1) {
        vs0 += __shfl_xor(vs0, o, 64); vs1 += __shfl_xor(vs1, o, 64);
        vs2 += __shfl_xor(vs2, o, 64); vs3 += __shfl_xor(vs3, o, 64);
        vd0 += __shfl_xor(vd0, o, 64); vd1 += __shfl_xor(vd1, o, 64);
        vd2 += __shfl_xor(vd2, o, 64); vd3 += __shfl_xor(vd3, o, 64);
    }
    if (lane == 0) {
        a_s[d] = make_float4(vs0, vs1, vs2, vs3);
        a_d[d] = make_float4(vd0, vd1, vd2, vd3);
    }
}

// ---------- FUSED attention + post-GEMM + residual/LN ----------
__global__ __launch_bounds__(256) void k_attn_post(
        const int* __restrict__ col, const int* __restrict__ row_ptr,
        const int* __restrict__ hist,
        const float4* __restrict__ a_s, const float4* __restrict__ a_d,
        const unsigned short* __restrict__ h1b,
        const unsigned short* __restrict__ Wt_g,
        const float* __restrict__ bp, const float* __restrict__ bg,
        const float* __restrict__ gamma, const float* __restrict__ beta,
        float* __restrict__ out, int n) {
    __shared__ unsigned short Atile[16 * APAD];   // 10.25 KB
    __shared__ float hbuf[16 * 68];               // 4.25 KB
    int t = threadIdx.x;
    int w = t >> 6, lane = t & 63, q = lane >> 4, li = lane & 15;
    int rowbase = blockIdx.x * 16;

    for (int j = 0; j < 4; j++) {
        int r = w * 4 + j;
        int d = rowbase + r;
        if (d >= n) {
            for (int c = lane; c < 320; c += 64) Atile[r * APAD + c] = 0;
            continue;
        }
        int start = row_ptr[d], cnt = hist[d];
        float4 ad = a_d[d];
        float4 asd = a_s[d];
        u16x4 sv = *(const u16x4*)(h1b + (size_t)d * HID + li * 4);
        // self edge (counted once, in quarter 0)
        float e0 = __expf(leaky(asd.x + ad.x));
        float e1 = __expf(leaky(asd.y + ad.y));
        float e2 = __expf(leaky(asd.z + ad.z));
        float e3 = __expf(leaky(asd.w + ad.w));
        float z = (q == 0) ? 1.0f : 0.0f;
        float f0 = bf2f(sv[0]), f1 = bf2f(sv[1]), f2 = bf2f(sv[2]), f3 = bf2f(sv[3]);
        f32x4 A0 = {z * e0 * f0, z * e0 * f1, z * e0 * f2, z * e0 * f3};
        f32x4 A1 = {z * e1 * f0, z * e1 * f1, z * e1 * f2, z * e1 * f3};
        f32x4 A2 = {z * e2 * f0, z * e2 * f1, z * e2 * f2, z * e2 * f3};
        f32x4 A3 = {z * e3 * f0, z * e3 * f1, z * e3 * f2, z * e3 * f3};
        float l0 = z * e0, l1 = z * e1, l2 = z * e2, l3 = z * e3;
        int k = q;
        int s = (k < cnt) ? col[start + k] : -1;
        while (s >= 0) {
            int k2 = k + 4;
            int s2 = (k2 < cnt) ? col[start + k2] : -1;   // prefetch next col chunk
            float4 as = a_s[s];
            u16x4 hv = *(const u16x4*)(h1b + (size_t)s * HID + li * 4);
            float w0 = __expf(leaky(as.x + ad.x));
            float w1 = __expf(leaky(as.y + ad.y));
            float w2 = __expf(leaky(as.z + ad.z));
            float w3 = __expf(leaky(as.w + ad.w));
            float g0 = bf2f(hv[0]), g1 = bf2f(hv[1]);
            float g2 = bf2f(hv[2]), g3 = bf2f(hv[3]);
            A0[0] += w0 * g0; A0[1] += w0 * g1; A0[2] += w0 * g2; A0[3] += w0 * g3;
            A1[0] += w1 * g0; A1[1] += w1 * g1; A1[2] += w1 * g2; A1[3] += w1 * g3;
            A2[0] += w2 * g0; A2[1] += w2 * g1; A2[2] += w2 * g2; A2[3] += w2 * g3;
            A3[0] += w3 * g0; A3[1] += w3 * g1; A3[2] += w3 * g2; A3[3] += w3 * g3;
            l0 += w0; l1 += w1; l2 += w2; l3 += w3;
            k = k2; s = s2;
        }
#pragma unroll
        for (int c4 = 0; c4 < 4; c4++) {
            A0[c4] += __shfl_xor(A0[c4], 16, 64);
            A1[c4] += __shfl_xor(A1[c4], 16, 64);
            A2[c4] += __shfl_xor(A2[c4], 16, 64);
            A3[c4] += __shfl_xor(A3[c4], 16, 64);
        }
        l0 += __shfl_xor(l0, 16, 64); l1 += __shfl_xor(l1, 16, 64);
        l2 += __shfl_xor(l2, 16, 64); l3 += __shfl_xor(l3, 16, 64);
#pragma unroll
        for (int c4 = 0; c4 < 4; c4++) {
            A0[c4] += __shfl_xor(A0[c4], 32, 64);
            A1[c4] += __shfl_xor(A1[c4], 32, 64);
            A2[c4] += __shfl_xor(A2[c4], 32, 64);
            A3[c4] += __shfl_xor(A3[c4], 32, 64);
        }
        l0 += __shfl_xor(l0, 32, 64); l1 += __shfl_xor(l1, 32, 64);
        l2 += __shfl_xor(l2, 32, 64); l3 += __shfl_xor(l3, 32, 64);
        // quarter q writes head q (static select -> cndmask, no scratch)
        f32x4 Aq; float lq;
        if (q == 0)      { Aq = A0; lq = l0; }
        else if (q == 1) { Aq = A1; lq = l1; }
        else if (q == 2) { Aq = A2; lq = l2; }
        else             { Aq = A3; lq = l3; }
        float inv = 1.0f / lq;
        u16x4 o;
        o[0] = f2bf(Aq[0] * inv); o[1] = f2bf(Aq[1] * inv);
        o[2] = f2bf(Aq[2] * inv); o[3] = f2bf(Aq[3] * inv);
        *(u16x4*)(&Atile[r * APAD + q * 64 + li * 4]) = o;
        if (q == 0) *(u16x4*)(&Atile[r * APAD + 256 + li * 4]) = sv;   // h1 row for ks=8,9 + residual
    }
    __syncthreads();

    // ---- Phase B: MFMA. Wave w -> out cols w*16..+15, rows 0..15. ----
    f32x4 acc_a = {0.f, 0.f, 0.f, 0.f}, acc_h = {0.f, 0.f, 0.f, 0.f};
#pragma unroll
    for (int ks = 0; ks < 10; ks++) {
        int kg = ks * 4 + q;
        bf16x8 a = *(const bf16x8*)(&Atile[li * APAD + ks * 32 + q * 8]);
        bf16x8 bb = *(const bf16x8*)(&Wt_g[(size_t)(kg * 64 + w * 16 + li) * 8]);
        if (ks < 8) acc_a = __builtin_amdgcn_mfma_f32_16x16x32_bf16(a, bb, acc_a, 0, 0, 0);
        else        acc_h = __builtin_amdgcn_mfma_f32_16x16x32_bf16(a, bb, acc_h, 0, 0, 0);
    }
    int cc = w * 16 + li;
    float bgv = bg[cc], bpv = bp[cc];
#pragma unroll
    for (int reg = 0; reg < 4; reg++) {
        int r = q * 4 + reg;
        float h1c = bf2f(Atile[r * APAD + 256 + cc]);
        float h2v = fmaxf(acc_a[reg] + bgv, 0.0f);
        hbuf[r * 68 + cc] = h1c + h2v + acc_h[reg] + bpv;
    }
    __syncthreads();

    // ---- Phase C: LayerNorm (16 threads per row, 4 cols each) ----
    int row = t >> 4, lj = t & 15;
    f32x4 hv4 = *(const f32x4*)(&hbuf[row * 68 + lj * 4]);
    float s1 = (hv4[0] + hv4[1]) + (hv4[2] + hv4[3]);
    float s2 = (hv4[0] * hv4[0] + hv4[1] * hv4[1]) + (hv4[2] * hv4[2] + hv4[3] * hv4[3]);
#pragma unroll
    for (int o = 1; o <= 8; o <<= 1) {
        s1 += __shfl_xor(s1, o, 64);
        s2 += __shfl_xor(s2, o, 64);
    }
    float mu = s1 * (1.0f / 64.0f);
    float var = s2 * (1.0f / 64.0f) - mu * mu;
    float rs = rsqrtf(var + LN_EPS);
    int rg = rowbase + row;
    if (rg < n) {
        float4 g4 = *(const float4*)(gamma + lj * 4);
        float4 b4 = *(const float4*)(beta + lj * 4);
        float4 ov;
        ov.x = (hv4[0] - mu) * rs * g4.x + b4.x;
        ov.y = (hv4[1] - mu) * rs * g4.y + b4.y;
        ov.z = (hv4[2] - mu) * rs * g4.z + b4.z;
        ov.w = (hv4[3] - mu) * rs * g4.w + b4.w;
        *(float4*)(out + (size_t)rg * HID + lj * 4) = ov;
    }
}

extern "C" void kernel_launch(void* const* d_in, const int* in_sizes, int n_in,
                              void* d_out, int out_size, void* d_ws, size_t ws_size,
                              hipStream_t stream) {
    int n = in_sizes[0] / IN_DIM;
    int E = in_sizes[1] / 2;

    const float* x     = (const float*)d_in[0];
    const void*  ei    = d_in[1];
    const float* W_gcn = (const float*)d_in[2];
    const float* b_gcn = (const float*)d_in[3];
    const float* W_gat = (const float*)d_in[4];
    const float* att_s = (const float*)d_in[5];
    const float* att_d = (const float*)d_in[6];
    const float* b_gat = (const float*)d_in[7];
    const float* W_p   = (const float*)d_in[8];
    const float* b_p   = (const float*)d_in[9];
    const float* gamma = (const float*)d_in[10];
    const float* beta  = (const float*)d_in[11];

    int n_pad  = ((n + 255) / 256) * 256;
    int n128   = ((n + 127) / 128) * 128;     // row padding for h1b

    float* ws = (float*)d_ws;
    size_t off = 0;
    int*   flag    = (int*)(ws + off);  off += 4;
    int*   hist    = (int*)(ws + off);  off += n;
    int*   row_ptr = (int*)(ws + off);  off += n;
    int*   cursor  = (int*)(ws + off);  off += n;
    int*   tmp     = (int*)(ws + off);  off += n_pad;
    int*   partial = (int*)(ws + off);  off += 256;
    int*   colv    = (int*)(ws + off);  off += E;
    float* dinv    = ws + off;          off += n;
    float* w_s     = ws + off;          off += HEADS * HID;
    float* w_d     = ws + off;          off += HEADS * HID;
    off = (off + 3) & ~(size_t)3;
    unsigned short* Wt_post = (unsigned short*)(ws + off); off += 2560 * 8 / 2;
    unsigned short* Wt_xw   = (unsigned short*)(ws + off); off += 1024 * 8 / 2;
    unsigned short* xws = (unsigned short*)(ws + off); off += (size_t)n * HID / 2;
    off = (off + 3) & ~(size_t)3;
    unsigned short* h1b = (unsigned short*)(ws + off); off += (size_t)n128 * HID / 2;
    off = (off + 3) & ~(size_t)3;
    float4* a_sv   = (float4*)(ws + off); off += (size_t)n * 4;
    float4* a_dv   = (float4*)(ws + off); off += (size_t)n * 4;

    // cooperative grid size: guaranteed co-resident
    static int s_grid = 0;
    if (s_grid == 0) {
        int occ = 0;
        hipOccupancyMaxActiveBlocksPerMultiprocessor(&occ, k_front, 256, 0);
        if (occ < 1) occ = 1;
        int sms = 0;
        hipDeviceProp_t prop;
        int dev = 0;
        if (hipGetDevice(&dev) == hipSuccess &&
            hipGetDeviceProperties(&prop, dev) == hipSuccess)
            sms = prop.multiProcessorCount;
        if (sms <= 0) sms = 256;
        s_grid = occ * sms;
    }
    int grid = s_grid;
    int needed = (E + 255) / 256;    // largest grid-stride workload
    if (grid > needed) grid = needed;
    if (grid < 1) grid = 1;

    const void* ei_a = ei; int E_a = E; int n_a = n;
    const float* x_a = x;
    const float* Wg_a = W_gat; const float* Wp_a = W_p; const float* Wgcn_a = W_gcn;
    const float* as_a = att_s; const float* ad_a = att_d;
    void* kargs[] = {
        (void*)&ei_a, &E_a, &n_a,
        &flag, &hist, &tmp, &partial,
        &row_ptr, &cursor, &colv, &dinv,
        (void*)&x_a,
        (void*)&Wg_a, (void*)&Wp_a, (void*)&Wgcn_a,
        (void*)&as_a, (void*)&ad_a,
        &Wt_post, &Wt_xw,
        &w_s, &w_d,
        &xws
    };
    hipLaunchCooperativeKernel(k_front, dim3(grid), dim3(256), kargs, 0, stream);

    // GCN gather (4-edge-wide) + logit dots
    k_gcn<<<(n + 3) / 4, 256, 0, stream>>>(colv, row_ptr, hist, dinv, xws, b_gcn,
                                           w_s, w_d, h1b, a_sv, a_dv, n);

    // FUSED attention + post GEMM + residual/LN
    k_attn_post<<<(n + 15) / 16, 256, 0, stream>>>(colv, row_ptr, hist, a_sv, a_dv,
                                                   h1b, Wt_post, b_p, b_gat,
                                                   gamma, beta, (float*)d_out, n);
}

// Round 3
// 209.063 us; speedup vs baseline: 2.1548x; 2.1548x over previous
//
#include <hip/hip_runtime.h>
#include <math.h>

#define IN_DIM 128
#define HID 64
#define HEADS 4
#define NEG_SLOPE 0.2f
#define LN_EPS 1e-5f
#define APAD 328            // Atile row pitch in bf16 elems (320 + 8 pad -> 2-way banks max)

typedef short bf16x8 __attribute__((ext_vector_type(8)));
typedef float f32x4  __attribute__((ext_vector_type(4)));
typedef unsigned short u16x4 __attribute__((ext_vector_type(4)));
typedef unsigned long long ull;

// ---------- bf16 helpers ----------
__device__ inline unsigned short f2bf(float f) {
    unsigned u = __float_as_uint(f);
    u += 0x7fffu + ((u >> 16) & 1u);     // round-to-nearest-even
    return (unsigned short)(u >> 16);
}
__device__ inline float bf2f(unsigned short s) {
    return __uint_as_float(((unsigned)s) << 16);
}
__device__ inline float leaky(float v) { return v > 0.0f ? v : NEG_SLOPE * v; }

// ---------- fused: weight pre-pack + att fold + flag + A-zero + dst histogram ----------
// hist must be pre-zeroed (hipMemsetAsync). Roles:
//   [0,14)  : pack Wt_post / Wt_xw
//   14      : fold w_s/w_d + write flag + zero lookback state A
//   [15, ..): histogram blocks (self-detect dtype; deterministic, all agree)
__global__ __launch_bounds__(256) void k_init(const void* ei, int E, int n,
                           int* flag, int* hist, ull* A,
                           const float* __restrict__ Wg, const float* __restrict__ Wp,
                           const float* __restrict__ Wgcn,
                           const float* __restrict__ att_s, const float* __restrict__ att_d,
                           unsigned short* __restrict__ Wt_post,
                           unsigned short* __restrict__ Wt_xw,
                           float* __restrict__ w_s, float* __restrict__ w_d) {
    int t = threadIdx.x;
    int role = blockIdx.x;
    if (role < 14) {
        int p = role * 256 + t;
        if (p < 2560) {
            int c = p & 63, kg = p >> 6;
            bf16x8 v;
#pragma unroll
            for (int j = 0; j < 8; j++) {
                int k = kg * 8 + j;
                float f;
                if (k < 256) f = 0.25f * Wg[(size_t)(k & 63) * 256 + (k >> 6) * 64 + c];
                else         f = Wp[(size_t)(k - 256) * 64 + c];
                v[j] = (short)f2bf(f);
            }
            *(bf16x8*)(&Wt_post[(size_t)p * 8]) = v;
        } else if (p < 2560 + 1024) {
            int q = p - 2560;
            int c = q & 63, kg = q >> 6;
            bf16x8 v;
#pragma unroll
            for (int j = 0; j < 8; j++)
                v[j] = (short)f2bf(Wgcn[(size_t)(kg * 8 + j) * 64 + c]);
            *(bf16x8*)(&Wt_xw[(size_t)q * 8]) = v;
        }
        return;
    }
    if (role == 14) {
        A[t] = 0ULL;                       // lookback state (nch <= 256)
        __shared__ int s_bad;
        if (t == 0) s_bad = 0;
        __syncthreads();
        int lim = E < 4096 ? E : 4096;
        int bad = 0;
        for (int k = t; k < lim; k += 256)
            if (((const ull*)ei)[k] >= (ull)n) bad = 1;
        if (bad) s_bad = 1;                // benign race
        __syncthreads();
        if (t == 0) *flag = s_bad ? 0 : 1; // 1 = genuine int64
        int h = t >> 6, k = t & 63;
        float ss = 0.0f, sd = 0.0f;
        for (int c = 0; c < HID; c++) {
            float w = Wg[(size_t)k * (HEADS * HID) + h * HID + c];
            ss += w * att_s[h * HID + c];
            sd += w * att_d[h * HID + c];
        }
        w_s[h * HID + k] = ss;
        w_d[h * HID + k] = sd;
        return;
    }
    // histogram blocks: self-detect dtype (same deterministic rule as flag block)
    __shared__ int s_bad2;
    if (t == 0) s_bad2 = 0;
    __syncthreads();
    int lim = E < 4096 ? E : 4096;
    int bad = 0;
    for (int k = t; k < lim; k += 256)
        if (((const ull*)ei)[k] >= (ull)n) bad = 1;
    if (bad) s_bad2 = 1;
    __syncthreads();
    int is64 = s_bad2 ? 0 : 1;
    int hb = role - 15;
    int nhb = gridDim.x - 15;
    for (int i = hb * 256 + t; i < E; i += nhb * 256) {
        int d;
        if (is64) d = (int)((const long long*)ei)[E + i];
        else      d = ((const int*)ei)[E + i];
        atomicAdd(&hist[d], 1);
    }
}

// ---------- single-kernel scan: per-chunk scan + wave-parallel decoupled lookback ----------
// A[c]: state<<32 | value. state 1 = aggregate ready, 2 = inclusive prefix ready.
__global__ __launch_bounds__(256) void k_scan_lb(const int* __restrict__ hist,
                                                 ull* __restrict__ A,
                                                 int* __restrict__ row_ptr,
                                                 int* __restrict__ cursor,
                                                 float* __restrict__ dinv, int n) {
    __shared__ int s[256];
    __shared__ int sbase;
    int t = threadIdx.x, c = blockIdx.x;
    int w = t >> 6, lane = t & 63;
    int i = c * 256 + t;
    int v = (i < n) ? hist[i] : 0;
    s[t] = v;
    __syncthreads();
    for (int off = 1; off < 256; off <<= 1) {
        int xv = (t >= off) ? s[t - off] : 0;
        __syncthreads();
        s[t] += xv;
        __syncthreads();
    }
    int incl = s[t];
    int S = s[255];
    if (t == 0) {
        if (c == 0) { sbase = 0; atomicExch(&A[0], (2ULL << 32) | (unsigned)S); }
        else          atomicExch(&A[c], (1ULL << 32) | (unsigned)S);
    }
    if (c > 0 && w == 0) {
        long long run = 0;
        int p = c - 1;
        for (;;) {
            int idx = p - lane;
            unsigned st, val;
            if (idx >= 0) {
                ull v2 = atomicAdd(&A[idx], 0ULL);
                st = (unsigned)(v2 >> 32); val = (unsigned)v2;
            } else { st = 2u; val = 0u; }
            ull pm = __ballot(st == 2);
            ull zm = __ballot(st == 0);
            int firstP = pm ? (__ffsll((long long)pm) - 1) : 64;
            int firstZ = zm ? (__ffsll((long long)zm) - 1) : 64;
            if (firstZ < firstP) { __builtin_amdgcn_s_sleep(1); continue; }
            unsigned contrib = (lane <= firstP) ? val : 0u;
#pragma unroll
            for (int o = 1; o <= 32; o <<= 1) contrib += __shfl_xor(contrib, o, 64);
            run += contrib;
            if (firstP < 64) break;
            p -= 64;
        }
        if (lane == 0) {
            sbase = (int)run;
            atomicExch(&A[c], (2ULL << 32) | (unsigned)(run + (unsigned)S));
        }
    }
    __syncthreads();
    if (i < n) {
        int excl = sbase + incl - v;
        row_ptr[i] = excl;
        cursor[i] = excl;
        dinv[i] = rsqrtf((float)(v + 1));   // +1 self-loop
    }
}

// ---------- fused: CSR scatter (from raw edge_index) + MFMA x@W_gcn ----------
__global__ __launch_bounds__(256) void k_scatter_xw(const void* ei, int E,
                                                    const int* __restrict__ flag,
                                                    int* __restrict__ cursor,
                                                    int* __restrict__ col,
                                                    const float* __restrict__ x,
                                                    const unsigned short* __restrict__ Wt_g,
                                                    const float* __restrict__ dinv,
                                                    unsigned short* __restrict__ xws, int n) {
    __shared__ unsigned short Wt[16 * 64 * 8];   // 16 KB (used by xw half only)
    int nsb = (E + 255) >> 8;
    if ((int)blockIdx.x < nsb) {
        int i = blockIdx.x * 256 + threadIdx.x;
        if (i >= E) return;
        int is64 = *flag;
        int s, d;
        if (is64) { s = (int)((const long long*)ei)[i]; d = (int)((const long long*)ei)[E + i]; }
        else      { s = ((const int*)ei)[i];            d = ((const int*)ei)[E + i]; }
        int pos = atomicAdd(&cursor[d], 1);
        col[pos] = s;
    } else {
        int bx = blockIdx.x - nsb;
        int t = threadIdx.x;
        for (int idx = t; idx < 1024; idx += 256)    // contiguous copy, conflict-free
            *(bf16x8*)(&Wt[idx * 8]) = *(const bf16x8*)(&Wt_g[(size_t)idx * 8]);
        __syncthreads();
        int lane = t & 63;
        int li = lane & 15, quad = lane >> 4;
        int w = t >> 6;
        int r0 = bx * 64 + w * 16;
        int rload = r0 + li; if (rload > n - 1) rload = n - 1;
        f32x4 acc[4];
#pragma unroll
        for (int i = 0; i < 4; i++) acc[i] = (f32x4){0.f, 0.f, 0.f, 0.f};
        const float* xp = x + (size_t)rload * IN_DIM + quad * 8;
#pragma unroll
        for (int ks = 0; ks < 4; ks++) {
            float4 p0 = *(const float4*)(xp + ks * 32);
            float4 p1 = *(const float4*)(xp + ks * 32 + 4);
            bf16x8 a;
            a[0] = (short)f2bf(p0.x); a[1] = (short)f2bf(p0.y);
            a[2] = (short)f2bf(p0.z); a[3] = (short)f2bf(p0.w);
            a[4] = (short)f2bf(p1.x); a[5] = (short)f2bf(p1.y);
            a[6] = (short)f2bf(p1.z); a[7] = (short)f2bf(p1.w);
            int kg = ks * 4 + quad;
#pragma unroll
            for (int tt = 0; tt < 4; tt++) {
                bf16x8 bfr = *(const bf16x8*)(&Wt[((kg * 64) + tt * 16 + li) * 8]);
                acc[tt] = __builtin_amdgcn_mfma_f32_16x16x32_bf16(a, bfr, acc[tt], 0, 0, 0);
            }
        }
#pragma unroll
        for (int reg = 0; reg < 4; reg++) {
            int r = r0 + quad * 4 + reg;
            if (r >= n) continue;
            float dv = dinv[r];
#pragma unroll
            for (int tt = 0; tt < 4; tt++)
                xws[(size_t)r * HID + tt * 16 + li] = f2bf(acc[tt][reg] * dv);
        }
    }
}

// ---------- GCN gather: 4-edge-wide + slim per-head epilogue ----------
// lane = q*16+li : quarter q handles edges k ≡ q (mod 4); li owns channels li*4..li*4+3.
// After xor(16,32) h is quarter-uniform; quarter q then computes ONLY head q's dots.
__global__ __launch_bounds__(256) void k_gcn(const int* __restrict__ col,
                                             const int* __restrict__ row_ptr,
                                             const int* __restrict__ hist,
                                             const float* __restrict__ dinv,
                                             const unsigned short* __restrict__ xws,
                                             const float* __restrict__ b,
                                             const float* __restrict__ w_s,
                                             const float* __restrict__ w_d,
                                             unsigned short* __restrict__ h1b,
                                             float4* __restrict__ a_s,
                                             float4* __restrict__ a_d, int n) {
    int t = threadIdx.x;
    int w = t >> 6, lane = t & 63, q = lane >> 4, li = lane & 15;
    int d = blockIdx.x * 4 + w;
    if (d >= n) return;
    int start = row_ptr[d], cnt = hist[d];
    float a0, a1, a2, a3;
    {
        u16x4 sv = *(const u16x4*)(xws + (size_t)d * HID + li * 4);
        float z = (q == 0) ? 1.0f : 0.0f;          // self term counted once
        a0 = z * bf2f(sv[0]); a1 = z * bf2f(sv[1]);
        a2 = z * bf2f(sv[2]); a3 = z * bf2f(sv[3]);
    }
    int k = q;
    int s = (k < cnt) ? col[start + k] : -1;
    while (s >= 0) {
        int k2 = k + 4;
        int s2 = (k2 < cnt) ? col[start + k2] : -1;   // prefetch next col chunk
        u16x4 v = *(const u16x4*)(xws + (size_t)s * HID + li * 4);
        a0 += bf2f(v[0]); a1 += bf2f(v[1]); a2 += bf2f(v[2]); a3 += bf2f(v[3]);
        k = k2; s = s2;
    }
    a0 += __shfl_xor(a0, 16, 64); a1 += __shfl_xor(a1, 16, 64);
    a2 += __shfl_xor(a2, 16, 64); a3 += __shfl_xor(a3, 16, 64);
    a0 += __shfl_xor(a0, 32, 64); a1 += __shfl_xor(a1, 32, 64);
    a2 += __shfl_xor(a2, 32, 64); a3 += __shfl_xor(a3, 32, 64);
    float dv = dinv[d];
    float4 bv = *(const float4*)(b + li * 4);
    float h0 = fmaxf(a0 * dv + bv.x, 0.0f);
    float h1 = fmaxf(a1 * dv + bv.y, 0.0f);
    float h2 = fmaxf(a2 * dv + bv.z, 0.0f);
    float h3 = fmaxf(a3 * dv + bv.w, 0.0f);
    if (q == 0) {
        u16x4 o;
        o[0] = f2bf(h0); o[1] = f2bf(h1); o[2] = f2bf(h2); o[3] = f2bf(h3);
        *(u16x4*)(h1b + (size_t)d * HID + li * 4) = o;
    }
    // quarter q computes head q's logit dots only
    float4 u  = *(const float4*)(w_s + q * 64 + li * 4);
    float vs = h0 * u.x + h1 * u.y + h2 * u.z + h3 * u.w;
    float4 u2 = *(const float4*)(w_d + q * 64 + li * 4);
    float vd = h0 * u2.x + h1 * u2.y + h2 * u2.z + h3 * u2.w;
#pragma unroll
    for (int o = 1; o <= 8; o <<= 1) {            // reduce over li (stays in quarter)
        vs += __shfl_xor(vs, o, 64);
        vd += __shfl_xor(vd, o, 64);
    }
    float vs1 = __shfl(vs, 16, 64), vs2 = __shfl(vs, 32, 64), vs3 = __shfl(vs, 48, 64);
    float vd1 = __shfl(vd, 16, 64), vd2 = __shfl(vd, 32, 64), vd3 = __shfl(vd, 48, 64);
    if (lane == 0) {
        a_s[d] = make_float4(vs, vs1, vs2, vs3);
        a_d[d] = make_float4(vd, vd1, vd2, vd3);
    }
}

// ---------- FUSED attention + post-GEMM + residual/LN ----------
__global__ __launch_bounds__(256) void k_attn_post(
        const int* __restrict__ col, const int* __restrict__ row_ptr,
        const int* __restrict__ hist,
        const float4* __restrict__ a_s, const float4* __restrict__ a_d,
        const unsigned short* __restrict__ h1b,
        const unsigned short* __restrict__ Wt_g,
        const float* __restrict__ bp, const float* __restrict__ bg,
        const float* __restrict__ gamma, const float* __restrict__ beta,
        float* __restrict__ out, int n) {
    __shared__ unsigned short Atile[16 * APAD];   // 10.25 KB
    __shared__ float hbuf[16 * 68];               // 4.25 KB
    int t = threadIdx.x;
    int w = t >> 6, lane = t & 63, q = lane >> 4, li = lane & 15;
    int rowbase = blockIdx.x * 16;

    for (int j = 0; j < 4; j++) {
        int r = w * 4 + j;
        int d = rowbase + r;
        if (d >= n) {
            for (int c = lane; c < 320; c += 64) Atile[r * APAD + c] = 0;
            continue;
        }
        int start = row_ptr[d], cnt = hist[d];
        float4 ad = a_d[d];
        float4 asd = a_s[d];
        u16x4 sv = *(const u16x4*)(h1b + (size_t)d * HID + li * 4);
        // self edge (counted once, in quarter 0)
        float e0 = __expf(leaky(asd.x + ad.x));
        float e1 = __expf(leaky(asd.y + ad.y));
        float e2 = __expf(leaky(asd.z + ad.z));
        float e3 = __expf(leaky(asd.w + ad.w));
        float z = (q == 0) ? 1.0f : 0.0f;
        float f0 = bf2f(sv[0]), f1 = bf2f(sv[1]), f2 = bf2f(sv[2]), f3 = bf2f(sv[3]);
        f32x4 A0 = {z * e0 * f0, z * e0 * f1, z * e0 * f2, z * e0 * f3};
        f32x4 A1 = {z * e1 * f0, z * e1 * f1, z * e1 * f2, z * e1 * f3};
        f32x4 A2 = {z * e2 * f0, z * e2 * f1, z * e2 * f2, z * e2 * f3};
        f32x4 A3 = {z * e3 * f0, z * e3 * f1, z * e3 * f2, z * e3 * f3};
        float l0 = z * e0, l1 = z * e1, l2 = z * e2, l3 = z * e3;
        int k = q;
        int s = (k < cnt) ? col[start + k] : -1;
        while (s >= 0) {
            int k2 = k + 4;
            int s2 = (k2 < cnt) ? col[start + k2] : -1;   // prefetch next col chunk
            float4 as = a_s[s];
            u16x4 hv = *(const u16x4*)(h1b + (size_t)s * HID + li * 4);
            float w0 = __expf(leaky(as.x + ad.x));
            float w1 = __expf(leaky(as.y + ad.y));
            float w2 = __expf(leaky(as.z + ad.z));
            float w3 = __expf(leaky(as.w + ad.w));
            float g0 = bf2f(hv[0]), g1 = bf2f(hv[1]);
            float g2 = bf2f(hv[2]), g3 = bf2f(hv[3]);
            A0[0] += w0 * g0; A0[1] += w0 * g1; A0[2] += w0 * g2; A0[3] += w0 * g3;
            A1[0] += w1 * g0; A1[1] += w1 * g1; A1[2] += w1 * g2; A1[3] += w1 * g3;
            A2[0] += w2 * g0; A2[1] += w2 * g1; A2[2] += w2 * g2; A2[3] += w2 * g3;
            A3[0] += w3 * g0; A3[1] += w3 * g1; A3[2] += w3 * g2; A3[3] += w3 * g3;
            l0 += w0; l1 += w1; l2 += w2; l3 += w3;
            k = k2; s = s2;
        }
#pragma unroll
        for (int c4 = 0; c4 < 4; c4++) {
            A0[c4] += __shfl_xor(A0[c4], 16, 64);
            A1[c4] += __shfl_xor(A1[c4], 16, 64);
            A2[c4] += __shfl_xor(A2[c4], 16, 64);
            A3[c4] += __shfl_xor(A3[c4], 16, 64);
        }
        l0 += __shfl_xor(l0, 16, 64); l1 += __shfl_xor(l1, 16, 64);
        l2 += __shfl_xor(l2, 16, 64); l3 += __shfl_xor(l3, 16, 64);
#pragma unroll
        for (int c4 = 0; c4 < 4; c4++) {
            A0[c4] += __shfl_xor(A0[c4], 32, 64);
            A1[c4] += __shfl_xor(A1[c4], 32, 64);
            A2[c4] += __shfl_xor(A2[c4], 32, 64);
            A3[c4] += __shfl_xor(A3[c4], 32, 64);
        }
        l0 += __shfl_xor(l0, 32, 64); l1 += __shfl_xor(l1, 32, 64);
        l2 += __shfl_xor(l2, 32, 64); l3 += __shfl_xor(l3, 32, 64);
        // quarter q writes head q (static select -> cndmask, no scratch)
        f32x4 Aq; float lq;
        if (q == 0)      { Aq = A0; lq = l0; }
        else if (q == 1) { Aq = A1; lq = l1; }
        else if (q == 2) { Aq = A2; lq = l2; }
        else             { Aq = A3; lq = l3; }
        float inv = 1.0f / lq;
        u16x4 o;
        o[0] = f2bf(Aq[0] * inv); o[1] = f2bf(Aq[1] * inv);
        o[2] = f2bf(Aq[2] * inv); o[3] = f2bf(Aq[3] * inv);
        *(u16x4*)(&Atile[r * APAD + q * 64 + li * 4]) = o;
        if (q == 0) *(u16x4*)(&Atile[r * APAD + 256 + li * 4]) = sv;   // h1 row for ks=8,9 + residual
    }
    __syncthreads();

    // ---- Phase B: MFMA. Wave w -> out cols w*16..+15, rows 0..15. ----
    f32x4 acc_a = {0.f, 0.f, 0.f, 0.f}, acc_h = {0.f, 0.f, 0.f, 0.f};
#pragma unroll
    for (int ks = 0; ks < 10; ks++) {
        int kg = ks * 4 + q;
        bf16x8 a = *(const bf16x8*)(&Atile[li * APAD + ks * 32 + q * 8]);
        bf16x8 bb = *(const bf16x8*)(&Wt_g[(size_t)(kg * 64 + w * 16 + li) * 8]);
        if (ks < 8) acc_a = __builtin_amdgcn_mfma_f32_16x16x32_bf16(a, bb, acc_a, 0, 0, 0);
        else        acc_h = __builtin_amdgcn_mfma_f32_16x16x32_bf16(a, bb, acc_h, 0, 0, 0);
    }
    int cc = w * 16 + li;
    float bgv = bg[cc], bpv = bp[cc];
#pragma unroll
    for (int reg = 0; reg < 4; reg++) {
        int r = q * 4 + reg;
        float h1c = bf2f(Atile[r * APAD + 256 + cc]);
        float h2v = fmaxf(acc_a[reg] + bgv, 0.0f);
        hbuf[r * 68 + cc] = h1c + h2v + acc_h[reg] + bpv;
    }
    __syncthreads();

    // ---- Phase C: LayerNorm (16 threads per row, 4 cols each) ----
    int row = t >> 4, lj = t & 15;
    f32x4 hv4 = *(const f32x4*)(&hbuf[row * 68 + lj * 4]);
    float s1 = (hv4[0] + hv4[1]) + (hv4[2] + hv4[3]);
    float s2 = (hv4[0] * hv4[0] + hv4[1] * hv4[1]) + (hv4[2] * hv4[2] + hv4[3] * hv4[3]);
#pragma unroll
    for (int o = 1; o <= 8; o <<= 1) {
        s1 += __shfl_xor(s1, o, 64);
        s2 += __shfl_xor(s2, o, 64);
    }
    float mu = s1 * (1.0f / 64.0f);
    float var = s2 * (1.0f / 64.0f) - mu * mu;
    float rs = rsqrtf(var + LN_EPS);
    int rg = rowbase + row;
    if (rg < n) {
        float4 g4 = *(const float4*)(gamma + lj * 4);
        float4 b4 = *(const float4*)(beta + lj * 4);
        float4 ov;
        ov.x = (hv4[0] - mu) * rs * g4.x + b4.x;
        ov.y = (hv4[1] - mu) * rs * g4.y + b4.y;
        ov.z = (hv4[2] - mu) * rs * g4.z + b4.z;
        ov.w = (hv4[3] - mu) * rs * g4.w + b4.w;
        *(float4*)(out + (size_t)rg * HID + lj * 4) = ov;
    }
}

extern "C" void kernel_launch(void* const* d_in, const int* in_sizes, int n_in,
                              void* d_out, int out_size, void* d_ws, size_t ws_size,
                              hipStream_t stream) {
    int n = in_sizes[0] / IN_DIM;
    int E = in_sizes[1] / 2;

    const float* x     = (const float*)d_in[0];
    const void*  ei    = d_in[1];
    const float* W_gcn = (const float*)d_in[2];
    const float* b_gcn = (const float*)d_in[3];
    const float* W_gat = (const float*)d_in[4];
    const float* att_s = (const float*)d_in[5];
    const float* att_d = (const float*)d_in[6];
    const float* b_gat = (const float*)d_in[7];
    const float* W_p   = (const float*)d_in[8];
    const float* b_p   = (const float*)d_in[9];
    const float* gamma = (const float*)d_in[10];
    const float* beta  = (const float*)d_in[11];

    int n128 = ((n + 127) / 128) * 128;     // row padding for h1b
    int nch  = (n + 255) / 256;             // scan chunks (must be <= 256 for A[])
    int nsb  = (E + 255) / 256;
    int nhb  = nsb < 1024 ? nsb : 1024;     // histogram blocks
    if (nhb < 1) nhb = 1;

    float* ws = (float*)d_ws;
    size_t off = 0;
    int*   flag    = (int*)(ws + off);  off += 4;
    int*   hist    = (int*)(ws + off);  off += n;
    int*   row_ptr = (int*)(ws + off);  off += n;
    int*   cursor  = (int*)(ws + off);  off += n;
    int*   colv    = (int*)(ws + off);  off += E;
    float* dinv    = ws + off;          off += n;
    float* w_s     = ws + off;          off += HEADS * HID;
    float* w_d     = ws + off;          off += HEADS * HID;
    off = (off + 1) & ~(size_t)1;       // 8B align for A
    ull*   A       = (ull*)(ws + off);  off += 512;   // 256 x u64
    off = (off + 3) & ~(size_t)3;
    unsigned short* Wt_post = (unsigned short*)(ws + off); off += 2560 * 8 / 2;
    unsigned short* Wt_xw   = (unsigned short*)(ws + off); off += 1024 * 8 / 2;
    unsigned short* xws = (unsigned short*)(ws + off); off += (size_t)n * HID / 2;
    off = (off + 3) & ~(size_t)3;
    unsigned short* h1b = (unsigned short*)(ws + off); off += (size_t)n128 * HID / 2;
    off = (off + 3) & ~(size_t)3;
    float4* a_sv   = (float4*)(ws + off); off += (size_t)n * 4;
    float4* a_dv   = (float4*)(ws + off); off += (size_t)n * 4;

    // zero hist (graph-capturable stream op), then fused init+histogram
    hipMemsetAsync(hist, 0, (size_t)n * sizeof(int), stream);
    k_init<<<15 + nhb, 256, 0, stream>>>(ei, E, n, flag, hist, A,
                                         W_gat, W_p, W_gcn, att_s, att_d,
                                         Wt_post, Wt_xw, w_s, w_d);

    // single-kernel scan with decoupled lookback -> row_ptr/cursor/dinv
    k_scan_lb<<<nch, 256, 0, stream>>>(hist, A, row_ptr, cursor, dinv, n);

    // fused: CSR scatter + MFMA x@W_gcn
    k_scatter_xw<<<nsb + (n + 63) / 64, 256, 0, stream>>>(ei, E, flag, cursor,
                                                          colv, x, Wt_xw,
                                                          dinv, xws, n);

    // GCN gather (4-edge-wide) + slim logit dots
    k_gcn<<<(n + 3) / 4, 256, 0, stream>>>(colv, row_ptr, hist, dinv, xws, b_gcn,
                                           w_s, w_d, h1b, a_sv, a_dv, n);

    // FUSED attention + post GEMM + residual/LN
    k_attn_post<<<(n + 15) / 16, 256, 0, stream>>>(colv, row_ptr, hist, a_sv, a_dv,
                                                   h1b, Wt_post, b_p, b_gat,
                                                   gamma, beta, (float*)d_out, n);
}